// Round 8
// baseline (387.871 us; speedup 1.0000x reference)
//
#include <hip/hip_runtime.h>

// DCMHAttention on MI355X (gfx950). Round 7: proj_softmax instruction diet —
// packed param layouts (f32x4 loads: 96->48 param load instrs) and wave-local
// LDS transpose-reduce (2 shfl instead of 96). Structure otherwise = R6.
// B=2 T=1024 D=2048 H=16 HD=128 K=128 IH=1. All GEMMs bf16 MFMA 16x16x32.

typedef unsigned short u16;
typedef unsigned int u32;
typedef __attribute__((ext_vector_type(8))) short s16x8;   // 8 x bf16 MFMA frag
typedef __attribute__((ext_vector_type(4))) float f32x4;   // MFMA accum
typedef __attribute__((ext_vector_type(2))) float f32x2;
typedef __attribute__((ext_vector_type(2))) u16 u16x2;

#define DEV __device__ __forceinline__

DEV float bf2f(u16 u) { union { u32 u; float f; } a; a.u = ((u32)u) << 16; return a.f; }
DEV u16 f2bf(float f) {
  union { float f; u32 u; } a; a.f = f;
  u32 r = a.u + 0x7fffu + ((a.u >> 16) & 1u);   // RNE
  return (u16)(r >> 16);
}

DEV void gload16(const void* g, void* l) {
  __builtin_amdgcn_global_load_lds((__attribute__((address_space(1))) void*)g,
                                   (__attribute__((address_space(3))) void*)l,
                                   16, 0, 0);
}

// ---------------------------------------------------------------------------
// Generic batched GEMM: C[z] = A[z] (MxK, row-major) * B[z]^T (B given as [N][K])
// 128x128 tile, BK=64, 4 waves each computing a 64x64 quadrant (4x4 frags).
// LDS XOR-swizzled (byte ^= (row&7)<<4) on both stage-source and read side.
// cmode: 0 = full; 1 = causal skip (exit if blockIdx.x > blockIdx.y);
//        2 = causal K-limit (Keff = (blockIdx.y+1)*128).
// ---------------------------------------------------------------------------
template <int OUTBF>
__global__ __launch_bounds__(256) void gemm_bt(
    const u16* __restrict__ A, const u16* __restrict__ B, void* __restrict__ Cp,
    int K, int lda, int ldb, int ldc,
    long sAb, long sBb, long sCb1, long sCb2, int CZ2, int cmode)
{
  if (cmode == 1 && blockIdx.x > blockIdx.y) return;
  __shared__ u16 sA[128 * 64];
  __shared__ u16 sB[128 * 64];
  const int tid = threadIdx.x, wv = tid >> 6, ln = tid & 63;
  const int z = blockIdx.z;
  const u16* Ab = A + (size_t)z * sAb + (size_t)(blockIdx.y * 128) * lda;
  const u16* Bb = B + (size_t)z * sBb + (size_t)(blockIdx.x * 128) * ldb;
  const int wr = (wv >> 1) * 64, wc = (wv & 1) * 64;
  const int Keff = (cmode == 2) ? min(K, ((int)blockIdx.y + 1) * 128) : K;

  f32x4 acc[4][4];
#pragma unroll
  for (int m = 0; m < 4; ++m)
#pragma unroll
    for (int n = 0; n < 4; ++n) {
      f32x4 zz = {0.f, 0.f, 0.f, 0.f};
      acc[m][n] = zz;
    }

  int o_[4], r_[4], cb_[4];
#pragma unroll
  for (int i = 0; i < 4; ++i) {
    int o = (wv * 4 + i) * 1024 + ln * 16;
    o_[i] = o;
    int r = o >> 7;
    r_[i] = r;
    cb_[i] = (o & 127) ^ ((r & 7) << 4);
  }
  const int frswz = (ln & 7) << 4;
  const int fkcol = (ln >> 4) << 4;

  for (int k0 = 0; k0 < Keff; k0 += 64) {
    __syncthreads();
#pragma unroll
    for (int i = 0; i < 4; ++i)
      gload16(Ab + (size_t)r_[i] * lda + (k0 + (cb_[i] >> 1)), (char*)sA + o_[i]);
#pragma unroll
    for (int i = 0; i < 4; ++i)
      gload16(Bb + (size_t)r_[i] * ldb + (k0 + (cb_[i] >> 1)), (char*)sB + o_[i]);
    __syncthreads();

#pragma unroll
    for (int ks = 0; ks < 2; ++ks) {
      s16x8 av[4], bv[4];
#pragma unroll
      for (int m = 0; m < 4; ++m) {
        int row = wr + m * 16 + (ln & 15);
        int addr = row * 128 + ((ks * 64 + fkcol) ^ frswz);
        av[m] = *(const s16x8*)((const char*)sA + addr);
      }
#pragma unroll
      for (int n = 0; n < 4; ++n) {
        int row = wc + n * 16 + (ln & 15);
        int addr = row * 128 + ((ks * 64 + fkcol) ^ frswz);
        bv[n] = *(const s16x8*)((const char*)sB + addr);
      }
#pragma unroll
      for (int m = 0; m < 4; ++m)
#pragma unroll
        for (int n = 0; n < 4; ++n)
          acc[m][n] = __builtin_amdgcn_mfma_f32_16x16x32_bf16(av[m], bv[n], acc[m][n], 0, 0, 0);
    }
  }

  const size_t cbase = (size_t)(z / CZ2) * sCb1 + (size_t)(z % CZ2) * sCb2;
  const int r0 = blockIdx.y * 128 + wr + ((ln >> 4) << 2);
  const int c0 = blockIdx.x * 128 + wc + (ln & 15);
#pragma unroll
  for (int m = 0; m < 4; ++m)
#pragma unroll
    for (int n = 0; n < 4; ++n)
#pragma unroll
      for (int j = 0; j < 4; ++j) {
        int row = r0 + m * 16 + j, col = c0 + n * 16;
        if (OUTBF)
          ((u16*)Cp)[cbase + (size_t)row * ldc + col] = f2bf(acc[m][n][j]);
        else
          ((float*)Cp)[cbase + (size_t)row * ldc + col] = acc[m][n][j];
      }
}

// ---------------------------------------------------------------------------
// Transpose (batched): dst[z][c][r] = src[z1*sSrc1+z2*sSrc2 + r*srcLd + c]
// INBF=0: f32 source; INBF=1: bf16 source. Output bf16, rows padded to Cpad.
// ---------------------------------------------------------------------------
template <int INBF>
__global__ __launch_bounds__(256) void transpose_to_bf16(
    const void* __restrict__ srcv, u16* __restrict__ dst,
    int R, int C, int Cpad, int srcLd, long sSrc1, long sSrc2, int Z2, long sDst)
{
  __shared__ float tile[32][33];
  const int z = blockIdx.z, z1 = z / Z2, z2 = z % Z2;
  const size_t sbase = (size_t)z1 * sSrc1 + (size_t)z2 * sSrc2;
  u16* d = dst + (size_t)z * sDst;
  const int c0 = blockIdx.x * 32, r0 = blockIdx.y * 32;
  const int tx = threadIdx.x, ty = threadIdx.y;
#pragma unroll
  for (int i = 0; i < 4; ++i) {
    int r = r0 + ty + i * 8, c = c0 + tx;
    float v = 0.f;
    if (c < C && r < R) {
      if (INBF) v = bf2f(((const u16*)srcv)[sbase + (size_t)r * srcLd + c]);
      else      v = ((const float*)srcv)[sbase + (size_t)r * srcLd + c];
    }
    tile[ty + i * 8][tx] = v;
  }
  __syncthreads();
#pragma unroll
  for (int i = 0; i < 4; ++i) {
    int dr = c0 + ty + i * 8, dc = r0 + tx;
    if (dr < Cpad && dc < R) d[(size_t)dr * R + dc] = f2bf(tile[tx][ty + i * 8]);
  }
}

__global__ void cvt_f32_bf16_k(const float* __restrict__ src, u16* __restrict__ dst, int n4) {
  int i = blockIdx.x * 256 + threadIdx.x;
  if (i >= n4) return;
  const float4 v = ((const float4*)src)[i];
  u16* o = dst + (size_t)i * 4;
  o[0] = f2bf(v.x); o[1] = f2bf(v.y); o[2] = f2bf(v.z); o[3] = f2bf(v.w);
}

// RoPE from bf16 qkv: reads split halves (j, j+64), writes interleaved. q scaled.
__global__ __launch_bounds__(256) void rope_k(
    const u16* __restrict__ qkvb, const float* __restrict__ fc,
    u16* __restrict__ qb, u16* __restrict__ kb)
{
  const int bt = blockIdx.x, b = bt >> 10, t = bt & 1023;
  const u16* row = qkvb + (size_t)bt * 6144;
  const float SC = 0.08838834764831845f;  // 128^-0.5
#pragma unroll
  for (int it = 0; it < 4; ++it) {
    int idx = threadIdx.x + it * 256;
    int h = idx >> 6, j = idx & 63;
    float c = fc[(t * 64 + j) * 2], sn = fc[(t * 64 + j) * 2 + 1];
    float qa = bf2f(row[h * 128 + j]), qbv = bf2f(row[h * 128 + 64 + j]);
    float ka = bf2f(row[2048 + h * 128 + j]), kbv = bf2f(row[2048 + h * 128 + 64 + j]);
    size_t o = ((size_t)(b * 16 + h) * 1024 + t) * 128 + 2 * j;
    qb[o]     = f2bf((qa * c - qbv * sn) * SC);
    qb[o + 1] = f2bf((qbv * c + qa * sn) * SC);
    kb[o]     = f2bf(ka * c - kbv * sn);
    kb[o + 1] = f2bf(kbv * c + ka * sn);
  }
}

__global__ void gelu_k(float* __restrict__ h, int n4) {
  int i = blockIdx.x * 256 + threadIdx.x;
  if (i >= n4) return;
  float4 v = ((float4*)h)[i];
  v.x = 0.5f * v.x * (1.f + erff(v.x * 0.70710678118654752f));
  v.y = 0.5f * v.y * (1.f + erff(v.y * 0.70710678118654752f));
  v.z = 0.5f * v.z * (1.f + erff(v.z * 0.70710678118654752f));
  v.w = 0.5f * v.w * (1.f + erff(v.w * 0.70710678118654752f));
  ((float4*)h)[i] = v;
}

// w = einsum(hid[bt,c,k], qkw[c,k,i,m]); w1 rms-normed over m. One wave per bt.
// Writes packed param layouts:
//  q-side: qparP[b][t][kind6][h16]          (kinds 0=pre_q1 1=pre_q2 3=post_q1 4=post_q2)
//  k-side: kpP [b][t/2][kind6][h16][t&1]    (kinds 0=pre_k1 1=pre_k2 3=post_k1 4=post_k2)
// kinds 2,5 (dd) written by dd_k.
__global__ __launch_bounds__(64) void wproj_k(
    const float* __restrict__ hid, const float* __restrict__ qkw,
    float* __restrict__ qparP, float* __restrict__ kpP)
{
  const int bt = blockIdx.x, ln = threadIdx.x;
  const int c = ln >> 4, m = ln & 15;
  const int b = bt >> 10, t = bt & 1023;
  const float* hp = hid + (size_t)bt * 512 + c * 128;
  const float* Wp = qkw + (size_t)c * 4096 + m;
  float w1 = 0.f, w2 = 0.f;
  for (int k = 0; k < 128; ++k) {
    float hv = hp[k];
    w1 += hv * Wp[k * 32];
    w2 += hv * Wp[k * 32 + 16];
  }
  float ss = w1 * w1;
  ss += __shfl_xor(ss, 1); ss += __shfl_xor(ss, 2);
  ss += __shfl_xor(ss, 4); ss += __shfl_xor(ss, 8);
  float nrm = rsqrtf(ss * (1.f / 16.f) + 1e-6f);
  float w1n = w1 * nrm;
  const size_t qb0 = (size_t)(b * 1024 + t) * 96;               // *6*16
  const size_t kb0 = (size_t)(b * 512 + (t >> 1)) * 192 + (size_t)m * 2 + (t & 1);
  if (c == 0) { qparP[qb0 + 0 * 16 + m] = w1n; qparP[qb0 + 1 * 16 + m] = w2; }
  if (c == 2) { qparP[qb0 + 3 * 16 + m] = w1n; qparP[qb0 + 4 * 16 + m] = w2; }
  if (c == 1) { kpP[kb0 + 0 * 32] = w1n; kpP[kb0 + 1 * 32] = w2; }
  if (c == 3) { kpP[kb0 + 3 * 32] = w1n; kpP[kb0 + 4 * 32] = w2; }
}

__global__ __launch_bounds__(64) void dd_k(const float* __restrict__ ddraw,
                                           float* __restrict__ qparP, float* __restrict__ kpP) {
  int bt = blockIdx.x, ln = threadIdx.x;
  int c = ln >> 4, m = ln & 15;
  int b = bt >> 10, t = bt & 1023;
  float v = tanhf(ddraw[(size_t)bt * 128 + ln]);
  const size_t qb0 = (size_t)(b * 1024 + t) * 96;
  const size_t kb0 = (size_t)(b * 512 + (t >> 1)) * 192 + (size_t)m * 2 + (t & 1);
  if (c == 0) qparP[qb0 + 2 * 16 + m] = v;
  if (c == 2) qparP[qb0 + 5 * 16 + m] = v;
  if (c == 1) kpP[kb0 + 2 * 32] = v;
  if (c == 3) kpP[kb0 + 5 * 32] = v;
}

// ---------------------------------------------------------------------------
// Fused: preproj(cross-head) -> causal mask -> softmax (no max; logits O(15))
// -> postproj -> P(bf16). One block per (b,t); 512 threads x 2 s-cols.
// Params via packed f32x4 loads; sum-reduce via wave-local LDS transpose
// (4 ds_write_b128 + 16 broadcast ds_read_b32 + 2 shfl per lane).
// ---------------------------------------------------------------------------
__global__ __launch_bounds__(512, 4) void proj_softmax_k(
    const float* __restrict__ L, u16* __restrict__ P,
    const float* __restrict__ qparP, const float* __restrict__ kpP)
{
  const int t = blockIdx.x, b = blockIdx.y;
  const int tid = threadIdx.x, wv = tid >> 6, ln = tid & 63;
  const int s0 = tid * 2;
  const bool live = (s0 <= t);

  __shared__ float qpar[6][16];
  __shared__ float tbuf[8][64][20];   // [wave][lane][16 heads + 4 pad]
  __shared__ float red2[16][8];
  __shared__ float rzf[16];
  if (tid < 96) qpar[tid >> 4][tid & 15] = qparP[(size_t)(b * 1024 + t) * 96 + tid];
  __syncthreads();

  const float* kp = kpP + (size_t)(b * 512 + tid) * 192;   // [kind][h][2]
  float v[16][2];
  const size_t lbase = ((size_t)(b * 16) * 1024 + t) * 1024 + s0;

  if (live) {
#pragma unroll
    for (int h = 0; h < 16; ++h) {
      f32x2 d = *(const f32x2*)(L + lbase + (size_t)h * 1048576);
      v[h][0] = d[0]; v[h][1] = d[1];
    }
    float dq0 = 0.f, dq1 = 0.f, dk0 = 0.f, dk1 = 0.f;
#pragma unroll
    for (int hp = 0; hp < 8; ++hp) {
      f32x4 k1 = *(const f32x4*)(kp + hp * 4);              // kind0: pre_k1
      int h0 = 2 * hp, h1 = 2 * hp + 1;
      dk0 += v[h0][0] * k1[0] + v[h1][0] * k1[2];
      dk1 += v[h0][1] * k1[1] + v[h1][1] * k1[3];
      dq0 += v[h0][0] * qpar[0][h0] + v[h1][0] * qpar[0][h1];
      dq1 += v[h0][1] * qpar[0][h0] + v[h1][1] * qpar[0][h1];
    }
    const bool ok1 = (s0 + 1 <= t);
#pragma unroll
    for (int hp = 0; hp < 8; ++hp) {
      f32x4 k2 = *(const f32x4*)(kp + 32 + hp * 4);         // kind1: pre_k2
      f32x4 kd = *(const f32x4*)(kp + 64 + hp * 4);         // kind2: pre_kdd
      int h0 = 2 * hp, h1 = 2 * hp + 1;
      float a00 = v[h0][0] * (1.f + qpar[2][h0] + kd[0]) + qpar[1][h0] * dq0 + k2[0] * dk0;
      float a01 = v[h0][1] * (1.f + qpar[2][h0] + kd[1]) + qpar[1][h0] * dq1 + k2[1] * dk1;
      float a10 = v[h1][0] * (1.f + qpar[2][h1] + kd[2]) + qpar[1][h1] * dq0 + k2[2] * dk0;
      float a11 = v[h1][1] * (1.f + qpar[2][h1] + kd[3]) + qpar[1][h1] * dq1 + k2[3] * dk1;
      v[h0][0] = __expf(a00); v[h0][1] = ok1 ? __expf(a01) : 0.f;
      v[h1][0] = __expf(a10); v[h1][1] = ok1 ? __expf(a11) : 0.f;
    }
  } else {
#pragma unroll
    for (int h = 0; h < 16; ++h) { v[h][0] = 0.f; v[h][1] = 0.f; }
  }

  // wave-local LDS transpose reduce of 16 head-partials
  {
    float* tb = &tbuf[wv][ln][0];
#pragma unroll
    for (int hp = 0; hp < 4; ++hp) {
      f32x4 p4;
      p4[0] = v[4 * hp + 0][0] + v[4 * hp + 0][1];
      p4[1] = v[4 * hp + 1][0] + v[4 * hp + 1][1];
      p4[2] = v[4 * hp + 2][0] + v[4 * hp + 2][1];
      p4[3] = v[4 * hp + 3][0] + v[4 * hp + 3][1];
      *(f32x4*)(tb + hp * 4) = p4;
    }
  }
  __syncthreads();
  {
    int h = ln & 15, q = ln >> 4;
    float sum = 0.f;
#pragma unroll
    for (int k = 0; k < 16; ++k) sum += tbuf[wv][q * 16 + k][h];
    sum += __shfl_xor(sum, 16);
    sum += __shfl_xor(sum, 32);
    if (ln < 16) red2[ln][wv] = sum;
  }
  __syncthreads();
  if (tid < 16)
    rzf[tid] = 1.f / (((red2[tid][0] + red2[tid][1]) + (red2[tid][2] + red2[tid][3])) +
                      ((red2[tid][4] + red2[tid][5]) + (red2[tid][6] + red2[tid][7])));
  __syncthreads();

  // post-projection + store P (bf16). Full range; masked -> exactly 0.
  const size_t pbase = ((size_t)(b * 16) * 1024 + t) * 1024 + s0;
  if (live) {
    float pdq0 = 0.f, pdq1 = 0.f, pdk0 = 0.f, pdk1 = 0.f;
#pragma unroll
    for (int hp = 0; hp < 8; ++hp) {
      f32x4 k1 = *(const f32x4*)(kp + 96 + hp * 4);         // kind3: post_k1
      int h0 = 2 * hp, h1 = 2 * hp + 1;
      float p00 = v[h0][0] * rzf[h0], p01 = v[h0][1] * rzf[h0];
      float p10 = v[h1][0] * rzf[h1], p11 = v[h1][1] * rzf[h1];
      v[h0][0] = p00; v[h0][1] = p01; v[h1][0] = p10; v[h1][1] = p11;
      pdq0 += p00 * qpar[3][h0] + p10 * qpar[3][h1];
      pdq1 += p01 * qpar[3][h0] + p11 * qpar[3][h1];
      pdk0 += p00 * k1[0] + p10 * k1[2];
      pdk1 += p01 * k1[1] + p11 * k1[3];
    }
#pragma unroll
    for (int hp = 0; hp < 8; ++hp) {
      f32x4 k2 = *(const f32x4*)(kp + 128 + hp * 4);        // kind4: post_k2
      f32x4 kd = *(const f32x4*)(kp + 160 + hp * 4);        // kind5: post_kdd
      int h0 = 2 * hp, h1 = 2 * hp + 1;
      u16x2 pk0, pk1;
      pk0[0] = f2bf(v[h0][0] * (1.f + qpar[5][h0] + kd[0]) + qpar[4][h0] * pdq0 + k2[0] * pdk0);
      pk0[1] = f2bf(v[h0][1] * (1.f + qpar[5][h0] + kd[1]) + qpar[4][h0] * pdq1 + k2[1] * pdk1);
      pk1[0] = f2bf(v[h1][0] * (1.f + qpar[5][h1] + kd[2]) + qpar[4][h1] * pdq0 + k2[2] * pdk0);
      pk1[1] = f2bf(v[h1][1] * (1.f + qpar[5][h1] + kd[3]) + qpar[4][h1] * pdq1 + k2[3] * pdk1);
      *(u16x2*)(P + pbase + (size_t)h0 * 1048576) = pk0;
      *(u16x2*)(P + pbase + (size_t)h1 * 1048576) = pk1;
    }
  } else {
    u16x2 z2 = {0, 0};
#pragma unroll
    for (int h = 0; h < 16; ++h)
      *(u16x2*)(P + pbase + (size_t)h * 1048576) = z2;
  }
}

// ---------------------------------------------------------------------------
extern "C" void kernel_launch(void* const* d_in, const int* in_sizes, int n_in,
                              void* d_out, int out_size, void* d_ws, size_t ws_size,
                              hipStream_t stream)
{
  (void)in_sizes; (void)n_in; (void)out_size; (void)ws_size;
  const float* x    = (const float*)d_in[0];
  const float* fc   = (const float*)d_in[2];
  const float* wqkv = (const float*)d_in[3];
  const float* wo   = (const float*)d_in[4];
  const float* dw1  = (const float*)d_in[5];
  const float* qkw  = (const float*)d_in[6];
  const float* ddw  = (const float*)d_in[7];
  float* out = (float*)d_out;
  char* w = (char*)d_ws;

  // persistent region
  u16*   woT   = (u16*)(w + 0);
  u16*   qb    = (u16*)(w + 8388608);
  u16*   kb    = (u16*)(w + 16777216);
  u16*   vT    = (u16*)(w + 25165824);
  u16*   obf   = (u16*)(w + 33554432);
  float* qparP = (float*)(w + 41943040);     // 2*1024*6*16 f32 = 768 KiB
  float* kpP   = (float*)(w + 42729472);     // 2*512*6*16*2 f32 = 768 KiB
  const size_t TB = 43515904;
  // transient layout A (dead before attention phase)
  u16*   xb    = (u16*)(w + TB);
  u16*   wqkvT = (u16*)(w + TB + 8388608);
  u16*   dw1T  = (u16*)(w + TB + 33554432);
  u16*   ddwT  = (u16*)(w + TB + 35651584);
  u16*   qkvb  = (u16*)(w + TB + 36175872);   // bf16 qkv, 2*1024*6144*2 = 25 MB
  float* hid   = (float*)(w + TB + 86507520);
  float* ddraw = (float*)(w + TB + 90701824);
  // transient layout B (attention) overlays layout A
  float* L     = (float*)(w + TB);
  u16*   P     = (u16*)(w + TB + 134217728);
  // total ws need: 244,842,496 bytes

  // input converts / transposes (to bf16, B^T layouts)
  cvt_f32_bf16_k<<<4096, 256, 0, stream>>>(x, xb, 1048576);
  transpose_to_bf16<0><<<dim3(192, 64, 1), dim3(32, 8), 0, stream>>>(wqkv, wqkvT, 2048, 6144, 6144, 6144, 0, 0, 1, 0);
  transpose_to_bf16<0><<<dim3(16, 64, 1),  dim3(32, 8), 0, stream>>>(dw1,  dw1T,  2048, 512,  512,  512,  0, 0, 1, 0);
  transpose_to_bf16<0><<<dim3(4, 64, 1),   dim3(32, 8), 0, stream>>>(ddw,  ddwT,  2048, 64,   128,  64,   0, 0, 1, 0);
  transpose_to_bf16<0><<<dim3(64, 64, 1),  dim3(32, 8), 0, stream>>>(wo,   woT,   2048, 2048, 2048, 2048, 0, 0, 1, 0);

  // qkv = x @ wqkv (bf16 out), then rope -> qb,kb, v -> vT [b,h,d,s]
  gemm_bt<1><<<dim3(48, 16, 1), 256, 0, stream>>>(xb, wqkvT, qkvb, 2048, 2048, 2048, 6144, 0, 0, 0, 0, 1, 0);
  rope_k<<<2048, 256, 0, stream>>>(qkvb, fc, qb, kb);
  transpose_to_bf16<1><<<dim3(4, 32, 32), dim3(32, 8), 0, stream>>>(qkvb + 4096, vT, 1024, 128, 128, 6144, 6291456, 128, 16, 131072);

  // dynamic-compose weights
  gemm_bt<0><<<dim3(4, 16, 1), 256, 0, stream>>>(xb, dw1T, hid, 2048, 2048, 2048, 512, 0, 0, 0, 0, 1, 0);
  gelu_k<<<1024, 256, 0, stream>>>(hid, 262144);
  gemm_bt<0><<<dim3(1, 16, 1), 256, 0, stream>>>(xb, ddwT, ddraw, 2048, 2048, 2048, 128, 0, 0, 0, 0, 1, 0);
  wproj_k<<<2048, 64, 0, stream>>>(hid, qkw, qparP, kpP);
  dd_k<<<2048, 64, 0, stream>>>(ddraw, qparP, kpP);

  // attention
  gemm_bt<0><<<dim3(8, 8, 32), 256, 0, stream>>>(qb, kb, L, 128, 128, 128, 1024, 131072, 131072, 1048576, 0, 1, 1);
  proj_softmax_k<<<dim3(1024, 2, 1), 512, 0, stream>>>(L, P, qparP, kpP);
  gemm_bt<1><<<dim3(1, 8, 32), 256, 0, stream>>>(P, vT, obf, 1024, 1024, 1024, 2048, 1048576, 131072, 2097152, 128, 16, 2);

  // out = o @ wo
  gemm_bt<0><<<dim3(16, 16, 1), 256, 0, stream>>>(obf, woT, out, 2048, 2048, 2048, 2048, 0, 0, 0, 0, 1, 0);
}

// Round 9
// 336.937 us; speedup vs baseline: 1.1512x; 1.1512x over previous
//
#include <hip/hip_runtime.h>

// DCMHAttention on MI355X (gfx950). Round 8: revert proj_softmax to R6 (R7's
// packed params broke coalescing, tbuf had 8-way bank conflicts). New: merge
// dd GEMM into dw-hidden GEMM (N=640, kills a 16-block dispatch); XCD swizzle
// on qkv/out GEMMs.
// B=2 T=1024 D=2048 H=16 HD=128 K=128 IH=1. All GEMMs bf16 MFMA 16x16x32.

typedef unsigned short u16;
typedef unsigned int u32;
typedef __attribute__((ext_vector_type(8))) short s16x8;   // 8 x bf16 MFMA frag
typedef __attribute__((ext_vector_type(4))) float f32x4;   // MFMA accum
typedef __attribute__((ext_vector_type(2))) float f32x2;
typedef __attribute__((ext_vector_type(2))) u16 u16x2;

#define DEV __device__ __forceinline__

DEV float bf2f(u16 u) { union { u32 u; float f; } a; a.u = ((u32)u) << 16; return a.f; }
DEV u16 f2bf(float f) {
  union { float f; u32 u; } a; a.f = f;
  u32 r = a.u + 0x7fffu + ((a.u >> 16) & 1u);   // RNE
  return (u16)(r >> 16);
}

DEV void gload16(const void* g, void* l) {
  __builtin_amdgcn_global_load_lds((__attribute__((address_space(1))) void*)g,
                                   (__attribute__((address_space(3))) void*)l,
                                   16, 0, 0);
}

// ---------------------------------------------------------------------------
// Generic batched GEMM: C[z] = A[z] (MxK, row-major) * B[z]^T (B given as [N][K])
// 128x128 tile, BK=64, 4 waves each computing a 64x64 quadrant (4x4 frags).
// LDS XOR-swizzled (byte ^= (row&7)<<4) on both stage-source and read side.
// cmode: 0 = full; 1 = causal skip (exit if bx > by);
//        2 = causal K-limit (Keff = (by+1)*128).
// swz: XCD-aware block swizzle (requires gridDim.x*gridDim.y % 8 == 0).
// ---------------------------------------------------------------------------
template <int OUTBF>
__global__ __launch_bounds__(256) void gemm_bt(
    const u16* __restrict__ A, const u16* __restrict__ B, void* __restrict__ Cp,
    int K, int lda, int ldb, int ldc,
    long sAb, long sBb, long sCb1, long sCb2, int CZ2, int cmode, int swz)
{
  int bx = blockIdx.x, by = blockIdx.y;
  if (swz) {
    int nx = gridDim.x;
    int fid = by * nx + bx;
    int cpx = (nx * gridDim.y) >> 3;
    int nid = (fid & 7) * cpx + (fid >> 3);
    bx = nid % nx; by = nid / nx;
  }
  if (cmode == 1 && bx > by) return;
  __shared__ u16 sA[128 * 64];
  __shared__ u16 sB[128 * 64];
  const int tid = threadIdx.x, wv = tid >> 6, ln = tid & 63;
  const int z = blockIdx.z;
  const u16* Ab = A + (size_t)z * sAb + (size_t)(by * 128) * lda;
  const u16* Bb = B + (size_t)z * sBb + (size_t)(bx * 128) * ldb;
  const int wr = (wv >> 1) * 64, wc = (wv & 1) * 64;
  const int Keff = (cmode == 2) ? min(K, (by + 1) * 128) : K;

  f32x4 acc[4][4];
#pragma unroll
  for (int m = 0; m < 4; ++m)
#pragma unroll
    for (int n = 0; n < 4; ++n) {
      f32x4 zz = {0.f, 0.f, 0.f, 0.f};
      acc[m][n] = zz;
    }

  int o_[4], r_[4], cb_[4];
#pragma unroll
  for (int i = 0; i < 4; ++i) {
    int o = (wv * 4 + i) * 1024 + ln * 16;
    o_[i] = o;
    int r = o >> 7;
    r_[i] = r;
    cb_[i] = (o & 127) ^ ((r & 7) << 4);
  }
  const int frswz = (ln & 7) << 4;
  const int fkcol = (ln >> 4) << 4;

  for (int k0 = 0; k0 < Keff; k0 += 64) {
    __syncthreads();
#pragma unroll
    for (int i = 0; i < 4; ++i)
      gload16(Ab + (size_t)r_[i] * lda + (k0 + (cb_[i] >> 1)), (char*)sA + o_[i]);
#pragma unroll
    for (int i = 0; i < 4; ++i)
      gload16(Bb + (size_t)r_[i] * ldb + (k0 + (cb_[i] >> 1)), (char*)sB + o_[i]);
    __syncthreads();

#pragma unroll
    for (int ks = 0; ks < 2; ++ks) {
      s16x8 av[4], bv[4];
#pragma unroll
      for (int m = 0; m < 4; ++m) {
        int row = wr + m * 16 + (ln & 15);
        int addr = row * 128 + ((ks * 64 + fkcol) ^ frswz);
        av[m] = *(const s16x8*)((const char*)sA + addr);
      }
#pragma unroll
      for (int n = 0; n < 4; ++n) {
        int row = wc + n * 16 + (ln & 15);
        int addr = row * 128 + ((ks * 64 + fkcol) ^ frswz);
        bv[n] = *(const s16x8*)((const char*)sB + addr);
      }
#pragma unroll
      for (int m = 0; m < 4; ++m)
#pragma unroll
        for (int n = 0; n < 4; ++n)
          acc[m][n] = __builtin_amdgcn_mfma_f32_16x16x32_bf16(av[m], bv[n], acc[m][n], 0, 0, 0);
    }
  }

  const size_t cbase = (size_t)(z / CZ2) * sCb1 + (size_t)(z % CZ2) * sCb2;
  const int r0 = by * 128 + wr + ((ln >> 4) << 2);
  const int c0 = bx * 128 + wc + (ln & 15);
#pragma unroll
  for (int m = 0; m < 4; ++m)
#pragma unroll
    for (int n = 0; n < 4; ++n)
#pragma unroll
      for (int j = 0; j < 4; ++j) {
        int row = r0 + m * 16 + j, col = c0 + n * 16;
        if (OUTBF)
          ((u16*)Cp)[cbase + (size_t)row * ldc + col] = f2bf(acc[m][n][j]);
        else
          ((float*)Cp)[cbase + (size_t)row * ldc + col] = acc[m][n][j];
      }
}

// ---------------------------------------------------------------------------
// Transpose (batched): dst[z][c][r] = src[z1*sSrc1+z2*sSrc2 + r*srcLd + c]
// INBF=0: f32 source; INBF=1: bf16 source. Output bf16, rows padded to Cpad.
// ---------------------------------------------------------------------------
template <int INBF>
__global__ __launch_bounds__(256) void transpose_to_bf16(
    const void* __restrict__ srcv, u16* __restrict__ dst,
    int R, int C, int Cpad, int srcLd, long sSrc1, long sSrc2, int Z2, long sDst)
{
  __shared__ float tile[32][33];
  const int z = blockIdx.z, z1 = z / Z2, z2 = z % Z2;
  const size_t sbase = (size_t)z1 * sSrc1 + (size_t)z2 * sSrc2;
  u16* d = dst + (size_t)z * sDst;
  const int c0 = blockIdx.x * 32, r0 = blockIdx.y * 32;
  const int tx = threadIdx.x, ty = threadIdx.y;
#pragma unroll
  for (int i = 0; i < 4; ++i) {
    int r = r0 + ty + i * 8, c = c0 + tx;
    float v = 0.f;
    if (c < C && r < R) {
      if (INBF) v = bf2f(((const u16*)srcv)[sbase + (size_t)r * srcLd + c]);
      else      v = ((const float*)srcv)[sbase + (size_t)r * srcLd + c];
    }
    tile[ty + i * 8][tx] = v;
  }
  __syncthreads();
#pragma unroll
  for (int i = 0; i < 4; ++i) {
    int dr = c0 + ty + i * 8, dc = r0 + tx;
    if (dr < Cpad && dc < R) d[(size_t)dr * R + dc] = f2bf(tile[tx][ty + i * 8]);
  }
}

__global__ void cvt_f32_bf16_k(const float* __restrict__ src, u16* __restrict__ dst, int n4) {
  int i = blockIdx.x * 256 + threadIdx.x;
  if (i >= n4) return;
  const float4 v = ((const float4*)src)[i];
  u16* o = dst + (size_t)i * 4;
  o[0] = f2bf(v.x); o[1] = f2bf(v.y); o[2] = f2bf(v.z); o[3] = f2bf(v.w);
}

// RoPE from bf16 qkv: reads split halves (j, j+64), writes interleaved. q scaled.
__global__ __launch_bounds__(256) void rope_k(
    const u16* __restrict__ qkvb, const float* __restrict__ fc,
    u16* __restrict__ qb, u16* __restrict__ kb)
{
  const int bt = blockIdx.x, b = bt >> 10, t = bt & 1023;
  const u16* row = qkvb + (size_t)bt * 6144;
  const float SC = 0.08838834764831845f;  // 128^-0.5
#pragma unroll
  for (int it = 0; it < 4; ++it) {
    int idx = threadIdx.x + it * 256;
    int h = idx >> 6, j = idx & 63;
    float c = fc[(t * 64 + j) * 2], sn = fc[(t * 64 + j) * 2 + 1];
    float qa = bf2f(row[h * 128 + j]), qbv = bf2f(row[h * 128 + 64 + j]);
    float ka = bf2f(row[2048 + h * 128 + j]), kbv = bf2f(row[2048 + h * 128 + 64 + j]);
    size_t o = ((size_t)(b * 16 + h) * 1024 + t) * 128 + 2 * j;
    qb[o]     = f2bf((qa * c - qbv * sn) * SC);
    qb[o + 1] = f2bf((qbv * c + qa * sn) * SC);
    kb[o]     = f2bf(ka * c - kbv * sn);
    kb[o + 1] = f2bf(kbv * c + ka * sn);
  }
}

// gelu on cols 0..511 of hidm rows (row stride 640)
__global__ __launch_bounds__(128) void gelu_k(float* __restrict__ hm) {
  int bt = blockIdx.x, tid = threadIdx.x;
  float* p = hm + (size_t)bt * 640 + tid * 4;
  float4 v = *(float4*)p;
  v.x = 0.5f * v.x * (1.f + erff(v.x * 0.70710678118654752f));
  v.y = 0.5f * v.y * (1.f + erff(v.y * 0.70710678118654752f));
  v.z = 0.5f * v.z * (1.f + erff(v.z * 0.70710678118654752f));
  v.w = 0.5f * v.w * (1.f + erff(v.w * 0.70710678118654752f));
  *(float4*)p = v;
}

// w = einsum(hid[bt,c,k], qkw[c,k,i,m]); w1 rms-normed over m. One wave per bt.
// hid rows have stride 640 (merged buffer). Also writes k-side params
// transposed: kparT[b][kind][h][s], kinds 0=pre_k1 1=pre_k2 3=post_k1
// 4=post_k2 (2,5 are dd, written by dd_k).
__global__ __launch_bounds__(64) void wproj_k(
    const float* __restrict__ hid, const float* __restrict__ qkw,
    float* __restrict__ w1a, float* __restrict__ w2a, float* __restrict__ kpT)
{
  const int bt = blockIdx.x, ln = threadIdx.x;
  const int c = ln >> 4, m = ln & 15;
  const int b = bt >> 10, t = bt & 1023;
  const float* hp = hid + (size_t)bt * 640 + c * 128;
  const float* Wp = qkw + (size_t)c * 4096 + m;
  float w1 = 0.f, w2 = 0.f;
  for (int k = 0; k < 128; ++k) {
    float hv = hp[k];
    w1 += hv * Wp[k * 32];
    w2 += hv * Wp[k * 32 + 16];
  }
  float ss = w1 * w1;
  ss += __shfl_xor(ss, 1); ss += __shfl_xor(ss, 2);
  ss += __shfl_xor(ss, 4); ss += __shfl_xor(ss, 8);
  float nrm = rsqrtf(ss * (1.f / 16.f) + 1e-6f);
  float w1n = w1 * nrm;
  size_t o = (size_t)bt * 64 + c * 16 + m;
  w1a[o] = w1n;
  w2a[o] = w2;
  size_t kb = (size_t)b * 98304 + (size_t)m * 1024 + t;
  if (c == 1) { kpT[kb] = w1n; kpT[kb + 16384] = w2; }
  if (c == 3) { kpT[kb + 49152] = w1n; kpT[kb + 65536] = w2; }
}

// dd from merged buffer cols 512..575 (row stride 640)
__global__ __launch_bounds__(64) void dd_k(const float* __restrict__ hm,
                                           float* __restrict__ dda, float* __restrict__ kpT) {
  int bt = blockIdx.x, ln = threadIdx.x;
  int c = ln >> 4, m = ln & 15;
  int b = bt >> 10, t = bt & 1023;
  float v = tanhf(hm[(size_t)bt * 640 + 512 + ln]);
  dda[(size_t)bt * 64 + ln] = v;
  size_t kb = (size_t)b * 98304 + (size_t)m * 1024 + t;
  if (c == 1) kpT[kb + 32768] = v;
  if (c == 3) kpT[kb + 81920] = v;
}

// ---------------------------------------------------------------------------
// Fused: preproj(cross-head) -> causal mask -> softmax (no max; logits O(15),
// shift-invariant, exp safe in f32) -> postproj -> P(bf16).  [R6 version]
// One block per (b,t); 512 threads x 2 s-cols x 16 heads. Sum reduction via
// wave shfl -> LDS -> 16-thread finalize. Full P written.
// ---------------------------------------------------------------------------
__global__ __launch_bounds__(512, 4) void proj_softmax_k(
    const float* __restrict__ L, u16* __restrict__ P,
    const float* __restrict__ w1a, const float* __restrict__ w2a,
    const float* __restrict__ dda, const float* __restrict__ kparT)
{
  const int t = blockIdx.x, b = blockIdx.y;
  const int tid = threadIdx.x, wv = tid >> 6, ln = tid & 63;
  const int s0 = tid * 2;
  const bool live = (s0 <= t);

  __shared__ float qpar[6][16];
  __shared__ float red2[16][8];
  __shared__ float rzf[16];
  if (tid < 96) {
    int a = tid >> 4, hh = tid & 15;
    const float* sp = (a == 0 || a == 3) ? w1a : ((a == 1 || a == 4) ? w2a : dda);
    int cc = (a < 3) ? 0 : 2;
    qpar[a][hh] = sp[(size_t)(b * 1024 + t) * 64 + cc * 16 + hh];
  }
  __syncthreads();

  const float* kp = kparT + (size_t)b * 98304 + s0;
  float v[16][2];
  const size_t lbase = ((size_t)(b * 16) * 1024 + t) * 1024 + s0;

  if (live) {
#pragma unroll
    for (int h = 0; h < 16; ++h) {
      f32x2 d = *(const f32x2*)(L + lbase + (size_t)h * 1048576);
      v[h][0] = d[0]; v[h][1] = d[1];
    }
    float dq0 = 0.f, dq1 = 0.f, dk0 = 0.f, dk1 = 0.f;
#pragma unroll
    for (int h = 0; h < 16; ++h) {
      f32x2 k1 = *(const f32x2*)(kp + h * 1024);
      dq0 += v[h][0] * qpar[0][h]; dq1 += v[h][1] * qpar[0][h];
      dk0 += v[h][0] * k1[0];      dk1 += v[h][1] * k1[1];
    }
    const bool ok1 = (s0 + 1 <= t);
#pragma unroll
    for (int h = 0; h < 16; ++h) {
      f32x2 k2 = *(const f32x2*)(kp + 16384 + h * 1024);
      f32x2 kd = *(const f32x2*)(kp + 32768 + h * 1024);
      float a0 = v[h][0] * (1.f + qpar[2][h] + kd[0]) + qpar[1][h] * dq0 + k2[0] * dk0;
      float a1 = v[h][1] * (1.f + qpar[2][h] + kd[1]) + qpar[1][h] * dq1 + k2[1] * dk1;
      v[h][0] = __expf(a0);
      v[h][1] = ok1 ? __expf(a1) : 0.f;
    }
  }

  // per-head sum -> LDS -> 16-thread finalize
#pragma unroll
  for (int h = 0; h < 16; ++h) {
    float x = live ? (v[h][0] + v[h][1]) : 0.f;
#pragma unroll
    for (int off = 32; off > 0; off >>= 1) x += __shfl_xor(x, off);
    if (ln == 0) red2[h][wv] = x;
  }
  __syncthreads();
  if (tid < 16)
    rzf[tid] = 1.f / (((red2[tid][0] + red2[tid][1]) + (red2[tid][2] + red2[tid][3])) +
                      ((red2[tid][4] + red2[tid][5]) + (red2[tid][6] + red2[tid][7])));
  __syncthreads();

  // post-projection + store P (bf16). Full range; masked -> exactly 0.
  const size_t pbase = ((size_t)(b * 16) * 1024 + t) * 1024 + s0;
  if (live) {
    float pdq0 = 0.f, pdq1 = 0.f, pdk0 = 0.f, pdk1 = 0.f;
#pragma unroll
    for (int h = 0; h < 16; ++h) {
      float rz = rzf[h];
      f32x2 k1 = *(const f32x2*)(kp + 49152 + h * 1024);
      float p0 = v[h][0] * rz, p1 = v[h][1] * rz;
      v[h][0] = p0; v[h][1] = p1;
      pdq0 += p0 * qpar[3][h]; pdq1 += p1 * qpar[3][h];
      pdk0 += p0 * k1[0];      pdk1 += p1 * k1[1];
    }
#pragma unroll
    for (int h = 0; h < 16; ++h) {
      f32x2 k2 = *(const f32x2*)(kp + 65536 + h * 1024);
      f32x2 kd = *(const f32x2*)(kp + 81920 + h * 1024);
      u16x2 pk;
      pk[0] = f2bf(v[h][0] * (1.f + qpar[5][h] + kd[0]) + qpar[4][h] * pdq0 + k2[0] * pdk0);
      pk[1] = f2bf(v[h][1] * (1.f + qpar[5][h] + kd[1]) + qpar[4][h] * pdq1 + k2[1] * pdk1);
      *(u16x2*)(P + pbase + (size_t)h * 1048576) = pk;
    }
  } else {
    u16x2 z2 = {0, 0};
#pragma unroll
    for (int h = 0; h < 16; ++h)
      *(u16x2*)(P + pbase + (size_t)h * 1048576) = z2;
  }
}

// ---------------------------------------------------------------------------
extern "C" void kernel_launch(void* const* d_in, const int* in_sizes, int n_in,
                              void* d_out, int out_size, void* d_ws, size_t ws_size,
                              hipStream_t stream)
{
  (void)in_sizes; (void)n_in; (void)out_size; (void)ws_size;
  const float* x    = (const float*)d_in[0];
  const float* fc   = (const float*)d_in[2];
  const float* wqkv = (const float*)d_in[3];
  const float* wo   = (const float*)d_in[4];
  const float* dw1  = (const float*)d_in[5];
  const float* qkw  = (const float*)d_in[6];
  const float* ddw  = (const float*)d_in[7];
  float* out = (float*)d_out;
  char* w = (char*)d_ws;

  // persistent region
  u16*   woT   = (u16*)(w + 0);
  u16*   qb    = (u16*)(w + 8388608);
  u16*   kb    = (u16*)(w + 16777216);
  u16*   vT    = (u16*)(w + 25165824);
  u16*   obf   = (u16*)(w + 33554432);
  float* w1a   = (float*)(w + 41943040);
  float* w2a   = (float*)(w + 42467328);
  float* dda   = (float*)(w + 42991616);
  const size_t TB = 43515904;
  // transient layout A (dead before attention phase)
  u16*   xb    = (u16*)(w + TB);
  u16*   wqkvT = (u16*)(w + TB + 8388608);
  u16*   dwddT = (u16*)(w + TB + 33554432);   // [640][2048] bf16 (512 dw1 + 64 ddw + pad)
  u16*   qkvb  = (u16*)(w + TB + 36175872);   // bf16 qkv, 25 MB
  float* hidm  = (float*)(w + TB + 61341696); // [2048][640] f32 merged hidden+ddraw
  // transient layout B (attention) overlays layout A
  float* L     = (float*)(w + TB);
  u16*   P     = (u16*)(w + TB + 134217728);
  float* kparT = (float*)(w + 244842496);     // 2*6*16*1024 f32 = 768 KiB
  // total ws need: 245,628,928 bytes

  // input converts / transposes (to bf16, B^T layouts)
  cvt_f32_bf16_k<<<4096, 256, 0, stream>>>(x, xb, 1048576);
  transpose_to_bf16<0><<<dim3(192, 64, 1), dim3(32, 8), 0, stream>>>(wqkv, wqkvT, 2048, 6144, 6144, 6144, 0, 0, 1, 0);
  transpose_to_bf16<0><<<dim3(16, 64, 1),  dim3(32, 8), 0, stream>>>(dw1,  dwddT, 2048, 512,  512,  512,  0, 0, 1, 0);
  transpose_to_bf16<0><<<dim3(4, 64, 1),   dim3(32, 8), 0, stream>>>(ddw,  dwddT + 512 * 2048, 2048, 64, 128, 64, 0, 0, 1, 0);
  transpose_to_bf16<0><<<dim3(64, 64, 1),  dim3(32, 8), 0, stream>>>(wo,   woT,   2048, 2048, 2048, 2048, 0, 0, 1, 0);

  // qkv = x @ wqkv (bf16 out, XCD-swizzled), then rope -> qb,kb, v -> vT
  gemm_bt<1><<<dim3(48, 16, 1), 256, 0, stream>>>(xb, wqkvT, qkvb, 2048, 2048, 2048, 6144, 0, 0, 0, 0, 1, 0, 1);
  rope_k<<<2048, 256, 0, stream>>>(qkvb, fc, qb, kb);
  transpose_to_bf16<1><<<dim3(4, 32, 32), dim3(32, 8), 0, stream>>>(qkvb + 4096, vT, 1024, 128, 128, 6144, 6291456, 128, 16, 131072);

  // dynamic-compose weights: merged hidden(512)+ddraw(64) GEMM, N=640
  gemm_bt<0><<<dim3(5, 16, 1), 256, 0, stream>>>(xb, dwddT, hidm, 2048, 2048, 2048, 640, 0, 0, 0, 0, 1, 0, 0);
  gelu_k<<<2048, 128, 0, stream>>>(hidm);
  wproj_k<<<2048, 64, 0, stream>>>(hidm, qkw, w1a, w2a, kparT);
  dd_k<<<2048, 64, 0, stream>>>(hidm, dda, kparT);

  // attention
  gemm_bt<0><<<dim3(8, 8, 32), 256, 0, stream>>>(qb, kb, L, 128, 128, 128, 1024, 131072, 131072, 1048576, 0, 1, 1, 0);
  proj_softmax_k<<<dim3(1024, 2, 1), 512, 0, stream>>>(L, P, w1a, w2a, dda, kparT);
  gemm_bt<1><<<dim3(1, 8, 32), 256, 0, stream>>>(P, vT, obf, 1024, 1024, 1024, 2048, 1048576, 131072, 2097152, 128, 16, 2, 0);

  // out = o @ wo (XCD-swizzled)
  gemm_bt<0><<<dim3(16, 16, 1), 256, 0, stream>>>(obf, woT, out, 2048, 2048, 2048, 2048, 0, 0, 0, 0, 1, 0, 1);
}